// Round 10
// baseline (216.686 us; speedup 1.0000x reference)
//
#include <hip/hip_runtime.h>
#include <hip/hip_bf16.h>
#include <math.h>

#define SELU_SCALE 1.0507009873554805f
#define SELU_ALPHA 1.6732632423543772f

static constexpr int B_ = 16, T_ = 16, L_ = 512, H_ = 768;

typedef __bf16 bf16x8 __attribute__((ext_vector_type(8)));
typedef __bf16 bf16x4 __attribute__((ext_vector_type(4)));
typedef float  f32x4  __attribute__((ext_vector_type(4)));

__device__ __forceinline__ float bf_lo(unsigned u) { return __uint_as_float(u << 16); }
__device__ __forceinline__ float bf_hi(unsigned u) { return __uint_as_float(u & 0xFFFF0000u); }

__device__ __forceinline__ float selu_core(float x) {
    float e = fmaf(__expf(x), SELU_ALPHA, -SELU_ALPHA);
    return x > 0.0f ? x : e;
}

__device__ __forceinline__ bf16x4 cvt4(float4 f) {
    bf16x4 o;
    o.x = (__bf16)f.x; o.y = (__bf16)f.y; o.z = (__bf16)f.z; o.w = (__bf16)f.w;
    return o;
}

__device__ __forceinline__ bf16x8 cvt8(float4 lo, float4 hi) {
    bf16x8 o;
    o[0] = (__bf16)lo.x; o[1] = (__bf16)lo.y; o[2] = (__bf16)lo.z; o[3] = (__bf16)lo.w;
    o[4] = (__bf16)hi.x; o[5] = (__bf16)hi.y; o[6] = (__bf16)hi.z; o[7] = (__bf16)hi.w;
    return o;
}

// ---------------- prep: W1/W2 -> bf16, dj gather (f32), zero out ----------------
__global__ __launch_bounds__(256) void prep_k(
        const float* __restrict__ w1, const float* __restrict__ w2,
        const float* __restrict__ dec, const int* __restrict__ Yi,
        __bf16* __restrict__ w1b, __bf16* __restrict__ w2b,
        float* __restrict__ djf, float* __restrict__ out) {
    const int NW = H_ * H_ / 4;                // 147456 float4s
    int i = blockIdx.x * 256 + threadIdx.x;
    if (i == 0) out[0] = 0.0f;
    if (i < NW) {
        ((bf16x4*)w1b)[i] = cvt4(((const float4*)w1)[i]);
    } else if (i < 2 * NW) {
        int j = i - NW;
        ((bf16x4*)w2b)[j] = cvt4(((const float4*)w2)[j]);
    } else {
        int j = i - 2 * NW;                    // < 49152
        int bt = j / 192, c = j % 192;
        int b = bt >> 4;
        int y = Yi[bt];
        ((float4*)djf)[bt * 192 + c] = ((const float4*)dec)[(b * L_ + y) * 192 + c];
    }
}

// ---------------- barrier-free no-LDS NT GEMM (WE + WD) -------------------------
// C[m][n] = sum_k A[m][k]*B[n][k]. Fragments read DIRECTLY from global (L1/L2):
// A f32 (cvt in-register), B bf16. No LDS, no s_barrier -- every LDS variant
// (r3/r6/r8/r9) pinned at ~35-44us with ~80% no-issue cycles from the
// synchronized barrier-cadence stall; here each wave free-runs its own
// prefetch-1 pipeline (static X/Y register sets). Wave tile 32x64 (2x4 MFMA
// 16x16x32), 4 waves -> block tile 64x128. XCD-aware mapping kept (same-m
// blocks stride 128 == 0 mod 8 -> same XCD L2, A fetched once per XCD).
__global__ __launch_bounds__(256, 3) void gemm_k(
        const float* __restrict__ hn, const float* __restrict__ djf,
        const __bf16* __restrict__ w1b, const __bf16* __restrict__ w2b,
        __bf16* __restrict__ web, __bf16* __restrict__ wdb) {
    int bx = blockIdx.x;
    const float* Af; const __bf16* Bw; __bf16* C; int m0, n0;
    if (bx < 768) {                       // WE: 128 m-tiles x 6 n-chunks
        Af = hn;  Bw = w1b; C = web;
        m0 = (bx & 127) * 64; n0 = (bx >> 7) * 128;
    } else {                              // WD: 4 m-tiles x 6 n-chunks
        bx -= 768;
        Af = djf; Bw = w2b; C = wdb;
        m0 = (bx & 3) * 64;   n0 = (bx >> 2) * 128;
    }

    const int tid = threadIdx.x;
    const int wave = tid >> 6, lane = tid & 63;
    const int wm = (wave & 1) * 32, wn = (wave >> 1) * 64;
    const int lr = lane & 15, q = lane >> 4;

    // per-lane fragment base pointers (16B/lane, 16 rows per frag)
    const float* Ap0 = Af + (size_t)(m0 + wm + lr) * 768 + q * 8;
    const float* Ap1 = Ap0 + (size_t)16 * 768;
    const __bf16* Bp0 = Bw + (size_t)(n0 + wn + lr) * 768 + q * 8;
    const __bf16* Bp1 = Bp0 + (size_t)16 * 768;
    const __bf16* Bp2 = Bp0 + (size_t)32 * 768;
    const __bf16* Bp3 = Bp0 + (size_t)48 * 768;

    f32x4 acc[2][4] = {};

    // prologue: k=0 -> set X, k=32 -> set Y
    float4 xa00 = *(const float4*)(Ap0);      float4 xa01 = *(const float4*)(Ap0 + 4);
    float4 xa10 = *(const float4*)(Ap1);      float4 xa11 = *(const float4*)(Ap1 + 4);
    uint4  xb0  = *(const uint4*)(Bp0);       uint4  xb1  = *(const uint4*)(Bp1);
    uint4  xb2  = *(const uint4*)(Bp2);       uint4  xb3  = *(const uint4*)(Bp3);
    float4 ya00 = *(const float4*)(Ap0 + 32); float4 ya01 = *(const float4*)(Ap0 + 36);
    float4 ya10 = *(const float4*)(Ap1 + 32); float4 ya11 = *(const float4*)(Ap1 + 36);
    uint4  yb0  = *(const uint4*)(Bp0 + 32);  uint4  yb1  = *(const uint4*)(Bp1 + 32);
    uint4  yb2  = *(const uint4*)(Bp2 + 32);  uint4  yb3  = *(const uint4*)(Bp3 + 32);

#pragma unroll 1
    for (int k0 = 0; k0 < 768; k0 += 64) {
        // ---- sub-iter X: compute tile k0, prefetch k0+64 into X ----
        {
            bf16x8 af0 = cvt8(xa00, xa01), af1 = cvt8(xa10, xa11);
            bf16x8 bf0 = __builtin_bit_cast(bf16x8, xb0);
            bf16x8 bf1 = __builtin_bit_cast(bf16x8, xb1);
            bf16x8 bf2 = __builtin_bit_cast(bf16x8, xb2);
            bf16x8 bf3 = __builtin_bit_cast(bf16x8, xb3);
            if (k0 + 64 < 768) {
                xa00 = *(const float4*)(Ap0 + k0 + 64); xa01 = *(const float4*)(Ap0 + k0 + 68);
                xa10 = *(const float4*)(Ap1 + k0 + 64); xa11 = *(const float4*)(Ap1 + k0 + 68);
                xb0  = *(const uint4*)(Bp0 + k0 + 64);  xb1  = *(const uint4*)(Bp1 + k0 + 64);
                xb2  = *(const uint4*)(Bp2 + k0 + 64);  xb3  = *(const uint4*)(Bp3 + k0 + 64);
            }
            acc[0][0] = __builtin_amdgcn_mfma_f32_16x16x32_bf16(af0, bf0, acc[0][0], 0, 0, 0);
            acc[0][1] = __builtin_amdgcn_mfma_f32_16x16x32_bf16(af0, bf1, acc[0][1], 0, 0, 0);
            acc[0][2] = __builtin_amdgcn_mfma_f32_16x16x32_bf16(af0, bf2, acc[0][2], 0, 0, 0);
            acc[0][3] = __builtin_amdgcn_mfma_f32_16x16x32_bf16(af0, bf3, acc[0][3], 0, 0, 0);
            acc[1][0] = __builtin_amdgcn_mfma_f32_16x16x32_bf16(af1, bf0, acc[1][0], 0, 0, 0);
            acc[1][1] = __builtin_amdgcn_mfma_f32_16x16x32_bf16(af1, bf1, acc[1][1], 0, 0, 0);
            acc[1][2] = __builtin_amdgcn_mfma_f32_16x16x32_bf16(af1, bf2, acc[1][2], 0, 0, 0);
            acc[1][3] = __builtin_amdgcn_mfma_f32_16x16x32_bf16(af1, bf3, acc[1][3], 0, 0, 0);
        }
        // ---- sub-iter Y: compute tile k0+32, prefetch k0+96 into Y ----
        {
            bf16x8 af0 = cvt8(ya00, ya01), af1 = cvt8(ya10, ya11);
            bf16x8 bf0 = __builtin_bit_cast(bf16x8, yb0);
            bf16x8 bf1 = __builtin_bit_cast(bf16x8, yb1);
            bf16x8 bf2 = __builtin_bit_cast(bf16x8, yb2);
            bf16x8 bf3 = __builtin_bit_cast(bf16x8, yb3);
            if (k0 + 96 < 768) {
                ya00 = *(const float4*)(Ap0 + k0 + 96); ya01 = *(const float4*)(Ap0 + k0 + 100);
                ya10 = *(const float4*)(Ap1 + k0 + 96); ya11 = *(const float4*)(Ap1 + k0 + 100);
                yb0  = *(const uint4*)(Bp0 + k0 + 96);  yb1  = *(const uint4*)(Bp1 + k0 + 96);
                yb2  = *(const uint4*)(Bp2 + k0 + 96);  yb3  = *(const uint4*)(Bp3 + k0 + 96);
            }
            acc[0][0] = __builtin_amdgcn_mfma_f32_16x16x32_bf16(af0, bf0, acc[0][0], 0, 0, 0);
            acc[0][1] = __builtin_amdgcn_mfma_f32_16x16x32_bf16(af0, bf1, acc[0][1], 0, 0, 0);
            acc[0][2] = __builtin_amdgcn_mfma_f32_16x16x32_bf16(af0, bf2, acc[0][2], 0, 0, 0);
            acc[0][3] = __builtin_amdgcn_mfma_f32_16x16x32_bf16(af0, bf3, acc[0][3], 0, 0, 0);
            acc[1][0] = __builtin_amdgcn_mfma_f32_16x16x32_bf16(af1, bf0, acc[1][0], 0, 0, 0);
            acc[1][1] = __builtin_amdgcn_mfma_f32_16x16x32_bf16(af1, bf1, acc[1][1], 0, 0, 0);
            acc[1][2] = __builtin_amdgcn_mfma_f32_16x16x32_bf16(af1, bf2, acc[1][2], 0, 0, 0);
            acc[1][3] = __builtin_amdgcn_mfma_f32_16x16x32_bf16(af1, bf3, acc[1][3], 0, 0, 0);
        }
    }

#pragma unroll
    for (int i = 0; i < 2; ++i)
#pragma unroll
        for (int j = 0; j < 4; ++j)
#pragma unroll
            for (int r = 0; r < 4; ++r) {
                int row = m0 + wm + i * 16 + q * 4 + r;
                int col = n0 + wn + j * 16 + lr;
                C[(size_t)row * 768 + col] = (__bf16)acc[i][j][r];
            }
}

// ---------------- fused scores: per-lane (t,l), no shuffles ----------------
__global__ __launch_bounds__(256) void scores_k(
        const __bf16* __restrict__ web, const __bf16* __restrict__ wdb,
        const float* __restrict__ V, const int* __restrict__ Xi,
        float* __restrict__ scores) {
    __shared__ float    we_s[16][772];
    __shared__ unsigned wd_s[16][388];
    __shared__ float    v_s[768];

    const int b = blockIdx.x, l0 = blockIdx.y * 16;

    for (int c = threadIdx.x; c < 16 * 96; c += 256) {
        int r = c / 96, cc = c % 96;
        uint4 v = *(const uint4*)(web + ((size_t)(b * L_ + l0 + r)) * H_ + cc * 8);
        float4 f0, f1;
        f0.x = bf_lo(v.x); f0.y = bf_hi(v.x); f0.z = bf_lo(v.y); f0.w = bf_hi(v.y);
        f1.x = bf_lo(v.z); f1.y = bf_hi(v.z); f1.z = bf_lo(v.w); f1.w = bf_hi(v.w);
        *(float4*)&we_s[r][cc * 8]     = f0;
        *(float4*)&we_s[r][cc * 8 + 4] = f1;
    }
    for (int c = threadIdx.x; c < 16 * 96; c += 256) {
        int r = c / 96, cc = c % 96;
        *(uint4*)&wd_s[r][cc * 4] = *(const uint4*)(wdb + ((size_t)(b * T_ + r)) * H_ + cc * 8);
    }
    if (threadIdx.x < 192) *(float4*)&v_s[threadIdx.x * 4] = ((const float4*)V)[threadIdx.x];
    __syncthreads();

    const int t = threadIdx.x >> 4;
    const int ls = threadIdx.x & 15;
    const int l = l0 + ls;
    const int X = Xi[b * T_ + t];
    if (!__any(l >= X)) return;

    float a0 = 0.f, a1 = 0.f, a2 = 0.f, a3 = 0.f;
#pragma unroll 4
    for (int h = 0; h < H_; h += 8) {
        float4 w0 = *(const float4*)&we_s[ls][h];
        float4 w1 = *(const float4*)&we_s[ls][h + 4];
        uint4  wd = *(const uint4*)&wd_s[t][h >> 1];
        float4 v0 = *(const float4*)&v_s[h];
        float4 v1 = *(const float4*)&v_s[h + 4];
        a0 = fmaf(selu_core(w0.x + bf_lo(wd.x)), v0.x, a0);
        a1 = fmaf(selu_core(w0.y + bf_hi(wd.x)), v0.y, a1);
        a2 = fmaf(selu_core(w0.z + bf_lo(wd.y)), v0.z, a2);
        a3 = fmaf(selu_core(w0.w + bf_hi(wd.y)), v0.w, a3);
        a0 = fmaf(selu_core(w1.x + bf_lo(wd.z)), v1.x, a0);
        a1 = fmaf(selu_core(w1.y + bf_hi(wd.z)), v1.y, a1);
        a2 = fmaf(selu_core(w1.z + bf_lo(wd.w)), v1.z, a2);
        a3 = fmaf(selu_core(w1.w + bf_hi(wd.w)), v1.w, a3);
    }
    float dot = SELU_SCALE * ((a0 + a1) + (a2 + a3));
    float sc  = dot > 0.0f ? SELU_SCALE * dot
                           : SELU_SCALE * SELU_ALPHA * (__expf(dot) - 1.0f);
    scores[((size_t)(b * T_ + t)) * L_ + l] = sc;
}

// ---------------- per-(b,t) masked logsumexp + gold + mean (atomic) -------------
__global__ __launch_bounds__(64) void loss_k(
        const float* __restrict__ scores, const int* __restrict__ Xi,
        const int* __restrict__ Yi, float* __restrict__ out) {
    const int bt = blockIdx.x;
    const int lane = threadIdx.x;
    const int X = Xi[bt];
    const int Y = Yi[bt];
    const float* row = scores + (size_t)bt * L_;

    float m = -INFINITY;
    for (int l = X + lane; l < L_; l += 64) m = fmaxf(m, row[l]);
#pragma unroll
    for (int off = 32; off > 0; off >>= 1) m = fmaxf(m, __shfl_xor(m, off));

    float s = 0.0f;
    for (int l = X + lane; l < L_; l += 64) s += __expf(row[l] - m);
#pragma unroll
    for (int off = 32; off > 0; off >>= 1) s += __shfl_xor(s, off);

    if (lane == 0)
        atomicAdd(out, (m + __logf(s) - row[Y]) * (1.0f / (B_ * T_)));
}

// ---------------- launch ----------------
extern "C" void kernel_launch(void* const* d_in, const int* in_sizes, int n_in,
                              void* d_out, int out_size, void* d_ws, size_t ws_size,
                              hipStream_t stream) {
    const float* hn  = (const float*)d_in[0];
    const float* dec = (const float*)d_in[1];
    const float* W1  = (const float*)d_in[2];
    const float* W2  = (const float*)d_in[3];
    const float* V   = (const float*)d_in[4];
    const int*   Xi  = (const int*)d_in[5];
    const int*   Yi  = (const int*)d_in[6];
    float* out = (float*)d_out;

    char* ws = (char*)d_ws;
    size_t off = 0;
    auto alloc = [&](size_t bytes) -> char* {
        char* p = ws + off;
        off += (bytes + 255) & ~(size_t)255;
        return p;
    };
    __bf16* w1b    = (__bf16*)alloc((size_t)H_ * H_ * 2);
    __bf16* w2b    = (__bf16*)alloc((size_t)H_ * H_ * 2);
    float*  djf    = (float*)alloc((size_t)B_ * T_ * H_ * 4);
    __bf16* web    = (__bf16*)alloc((size_t)B_ * L_ * H_ * 2);
    __bf16* wdb    = (__bf16*)alloc((size_t)B_ * T_ * H_ * 2);
    float*  scores = (float*)alloc((size_t)B_ * T_ * L_ * 4);

    // prep: (2*147456 + 49152) / 256 = 1344 blocks
    prep_k<<<1344, 256, 0, stream>>>(W1, W2, dec, Yi, w1b, w2b, djf, out);
    // WE (768 blocks, XCD-swizzled) + WD (24 blocks): no-LDS, barrier-free
    gemm_k<<<792, 256, 0, stream>>>(hn, djf, w1b, w2b, web, wdb);
    scores_k<<<dim3(B_, L_ / 16), 256, 0, stream>>>(web, wdb, V, Xi, scores);
    loss_k<<<B_ * T_, 64, 0, stream>>>(scores, Xi, Yi, out);
}

// Round 12
// 152.419 us; speedup vs baseline: 1.4217x; 1.4217x over previous
//
#include <hip/hip_runtime.h>
#include <hip/hip_bf16.h>
#include <math.h>

#define SELU_SCALE 1.0507009873554805f
#define SELU_ALPHA 1.6732632423543772f

static constexpr int B_ = 16, T_ = 16, L_ = 512, H_ = 768;

typedef __bf16 bf16x8 __attribute__((ext_vector_type(8)));
typedef float  f32x4  __attribute__((ext_vector_type(4)));

__device__ __forceinline__ float bf_lo(unsigned u) { return __uint_as_float(u << 16); }
__device__ __forceinline__ float bf_hi(unsigned u) { return __uint_as_float(u & 0xFFFF0000u); }

__device__ __forceinline__ float selu_core(float x) {
    float e = fmaf(__expf(x), SELU_ALPHA, -SELU_ALPHA);
    return x > 0.0f ? x : e;
}

// LDS k-segment slot swizzle: slot = seg ^ ((row>>1)&3). r6 measured 0 conflicts
// for these write/read patterns (16-row x 64B contiguous 1KB per wave-op).
__device__ __forceinline__ int xsw(int r) { return (r >> 1) & 3; }

__device__ __forceinline__ bf16x8 pack8(float4 a, float4 b) {
    bf16x8 o;
    o[0] = (__bf16)a.x; o[1] = (__bf16)a.y; o[2] = (__bf16)a.z; o[3] = (__bf16)a.w;
    o[4] = (__bf16)b.x; o[5] = (__bf16)b.y; o[6] = (__bf16)b.z; o[7] = (__bf16)b.w;
    return o;
}

// ---------------- fused NT GEMM (WE + WD), no prep pass -------------------------
// C[m][n] = sum_k A[m][k]*B[n][k]. A and B both f32 in HBM (hn / W1; dec-gather /
// W2 for WD blocks), converted to bf16 in-register during staging. 128x128 block
// tile, 4 waves of 64x64 (4x4 MFMA 16x16x32) -> 0.5 LDS reads per MFMA (vs 0.75
// in r9 -- LDS pipe is the measured binder: 24 reads+12 writes/iter vs 155 cyc
// MFMA). BK=32, prefetch distance 2, statically-named X/Y register sets
// (r7's dynamic indexing caused LDS-promotion+scratch). XCD-aware: same-m blocks
// at stride 64 == 0 mod 8 -> same XCD L2, hn fetched once per XCD.
__global__ __launch_bounds__(256, 2) void gemm_k(
        const float* __restrict__ hn, const float* __restrict__ dec,
        const float* __restrict__ w1, const float* __restrict__ w2,
        const int* __restrict__ Yi,
        __bf16* __restrict__ web, __bf16* __restrict__ wdb,
        float* __restrict__ out) {
    __shared__ __bf16 As[128 * 32];   // 8 KB
    __shared__ __bf16 Bs[128 * 32];   // 8 KB

    const int tid = threadIdx.x;
    if (blockIdx.x == 0 && tid == 0) out[0] = 0.0f;   // for loss_k atomics

    int bx = blockIdx.x;
    const float* Wf; __bf16* C; int m0, n0; bool wd;
    if (bx < 384) {                      // WE: 64 m-tiles x 6 n-chunks
        wd = false; Wf = w1; C = web;
        m0 = (bx & 63) * 128; n0 = (bx >> 6) * 128;
    } else {                             // WD: 2 m-tiles x 6 n-chunks
        wd = true; bx -= 384; Wf = w2; C = wdb;
        m0 = (bx & 1) * 128;  n0 = (bx >> 1) * 128;
    }

    const int wave = tid >> 6, lane = tid & 63;
    const int wm = (wave >> 1) * 64, wn = (wave & 1) * 64;
    const int lr = lane & 15, q = lane >> 4;

    // staging: thread -> rows r1 = wave*32+(lane>>2), r2 = r1+16; slot s3 = lane&3
    // holds global k-seg g1 = s3 ^ xsw(r1)  (xsw(r1) == xsw(r1+16))
    const int r1 = wave * 32 + (lane >> 2);
    const int s3 = lane & 3;
    const int g1 = s3 ^ xsw(r1);

    const float *aG1, *aG2;
    if (!wd) {
        aG1 = hn + (size_t)(m0 + r1) * 768 + g1 * 8;
        aG2 = aG1 + (size_t)16 * 768;
    } else {
        int bt1 = m0 + r1, bt2 = bt1 + 16;
        aG1 = dec + ((size_t)((bt1 >> 4) * L_ + Yi[bt1])) * 768 + g1 * 8;
        aG2 = dec + ((size_t)((bt2 >> 4) * L_ + Yi[bt2])) * 768 + g1 * 8;
    }
    const float* bG1 = Wf + (size_t)(n0 + r1) * 768 + g1 * 8;
    const float* bG2 = bG1 + (size_t)16 * 768;

    bf16x8* AsW1 = (bf16x8*)&As[r1 * 32 + s3 * 8];
    bf16x8* AsW2 = (bf16x8*)&As[(r1 + 16) * 32 + s3 * 8];
    bf16x8* BsW1 = (bf16x8*)&Bs[r1 * 32 + s3 * 8];
    bf16x8* BsW2 = (bf16x8*)&Bs[(r1 + 16) * 32 + s3 * 8];

    // fragment read offsets (global seg q at slot q^xsw(row))
    int aoff[4], boff[4];
#pragma unroll
    for (int i = 0; i < 4; ++i) {
        int r = wm + i * 16 + lr;
        aoff[i] = r * 32 + (q ^ xsw(r)) * 8;
    }
#pragma unroll
    for (int j = 0; j < 4; ++j) {
        int r = wn + j * 16 + lr;
        boff[j] = r * 32 + (q ^ xsw(r)) * 8;
    }

    f32x4 acc[4][4] = {};

    // prologue: tile k=0 -> set X, tile k=32 -> set Y (statically named)
    float4 xa1a = *(const float4*)(aG1);      float4 xa1b = *(const float4*)(aG1 + 4);
    float4 xa2a = *(const float4*)(aG2);      float4 xa2b = *(const float4*)(aG2 + 4);
    float4 xb1a = *(const float4*)(bG1);      float4 xb1b = *(const float4*)(bG1 + 4);
    float4 xb2a = *(const float4*)(bG2);      float4 xb2b = *(const float4*)(bG2 + 4);
    float4 ya1a = *(const float4*)(aG1 + 32); float4 ya1b = *(const float4*)(aG1 + 36);
    float4 ya2a = *(const float4*)(aG2 + 32); float4 ya2b = *(const float4*)(aG2 + 36);
    float4 yb1a = *(const float4*)(bG1 + 32); float4 yb1b = *(const float4*)(bG1 + 36);
    float4 yb2a = *(const float4*)(bG2 + 32); float4 yb2b = *(const float4*)(bG2 + 36);

#pragma unroll 1
    for (int k0 = 0; k0 < 768; k0 += 64) {
        // ======== sub-iter X: tile k0 ========
        {
            *AsW1 = pack8(xa1a, xa1b);
            *AsW2 = pack8(xa2a, xa2b);
            *BsW1 = pack8(xb1a, xb1b);
            *BsW2 = pack8(xb2a, xb2b);
            asm volatile("s_waitcnt lgkmcnt(0)\n\ts_barrier" ::: "memory");
            if (k0 + 64 < 768) {
                xa1a = *(const float4*)(aG1 + k0 + 64); xa1b = *(const float4*)(aG1 + k0 + 68);
                xa2a = *(const float4*)(aG2 + k0 + 64); xa2b = *(const float4*)(aG2 + k0 + 68);
                xb1a = *(const float4*)(bG1 + k0 + 64); xb1b = *(const float4*)(bG1 + k0 + 68);
                xb2a = *(const float4*)(bG2 + k0 + 64); xb2b = *(const float4*)(bG2 + k0 + 68);
            }
            bf16x8 af[4], bfr[4];
#pragma unroll
            for (int i = 0; i < 4; ++i) af[i]  = *(const bf16x8*)&As[aoff[i]];
#pragma unroll
            for (int j = 0; j < 4; ++j) bfr[j] = *(const bf16x8*)&Bs[boff[j]];
#pragma unroll
            for (int i = 0; i < 4; ++i)
#pragma unroll
                for (int j = 0; j < 4; ++j)
                    acc[i][j] = __builtin_amdgcn_mfma_f32_16x16x32_bf16(af[i], bfr[j], acc[i][j], 0, 0, 0);
            asm volatile("s_barrier" ::: "memory");
        }
        // ======== sub-iter Y: tile k0+32 ========
        {
            *AsW1 = pack8(ya1a, ya1b);
            *AsW2 = pack8(ya2a, ya2b);
            *BsW1 = pack8(yb1a, yb1b);
            *BsW2 = pack8(yb2a, yb2b);
            asm volatile("s_waitcnt lgkmcnt(0)\n\ts_barrier" ::: "memory");
            if (k0 + 96 < 768) {
                ya1a = *(const float4*)(aG1 + k0 + 96); ya1b = *(const float4*)(aG1 + k0 + 100);
                ya2a = *(const float4*)(aG2 + k0 + 96); ya2b = *(const float4*)(aG2 + k0 + 100);
                yb1a = *(const float4*)(bG1 + k0 + 96); yb1b = *(const float4*)(bG1 + k0 + 100);
                yb2a = *(const float4*)(bG2 + k0 + 96); yb2b = *(const float4*)(bG2 + k0 + 100);
            }
            bf16x8 af[4], bfr[4];
#pragma unroll
            for (int i = 0; i < 4; ++i) af[i]  = *(const bf16x8*)&As[aoff[i]];
#pragma unroll
            for (int j = 0; j < 4; ++j) bfr[j] = *(const bf16x8*)&Bs[boff[j]];
#pragma unroll
            for (int i = 0; i < 4; ++i)
#pragma unroll
                for (int j = 0; j < 4; ++j)
                    acc[i][j] = __builtin_amdgcn_mfma_f32_16x16x32_bf16(af[i], bfr[j], acc[i][j], 0, 0, 0);
            asm volatile("s_barrier" ::: "memory");
        }
    }

#pragma unroll
    for (int i = 0; i < 4; ++i)
#pragma unroll
        for (int j = 0; j < 4; ++j)
#pragma unroll
            for (int r = 0; r < 4; ++r) {
                int row = m0 + wm + i * 16 + q * 4 + r;
                int col = n0 + wn + j * 16 + lr;
                C[(size_t)row * 768 + col] = (__bf16)acc[i][j][r];
            }
}

// ---------------- fused scores: per-lane (t,l), no shuffles ----------------
__global__ __launch_bounds__(256) void scores_k(
        const __bf16* __restrict__ web, const __bf16* __restrict__ wdb,
        const float* __restrict__ V, const int* __restrict__ Xi,
        float* __restrict__ scores) {
    __shared__ float    we_s[16][772];
    __shared__ unsigned wd_s[16][388];
    __shared__ float    v_s[768];

    const int b = blockIdx.x, l0 = blockIdx.y * 16;

    for (int c = threadIdx.x; c < 16 * 96; c += 256) {
        int r = c / 96, cc = c % 96;
        uint4 v = *(const uint4*)(web + ((size_t)(b * L_ + l0 + r)) * H_ + cc * 8);
        float4 f0, f1;
        f0.x = bf_lo(v.x); f0.y = bf_hi(v.x); f0.z = bf_lo(v.y); f0.w = bf_hi(v.y);
        f1.x = bf_lo(v.z); f1.y = bf_hi(v.z); f1.z = bf_lo(v.w); f1.w = bf_hi(v.w);
        *(float4*)&we_s[r][cc * 8]     = f0;
        *(float4*)&we_s[r][cc * 8 + 4] = f1;
    }
    for (int c = threadIdx.x; c < 16 * 96; c += 256) {
        int r = c / 96, cc = c % 96;
        *(uint4*)&wd_s[r][cc * 4] = *(const uint4*)(wdb + ((size_t)(b * T_ + r)) * H_ + cc * 8);
    }
    if (threadIdx.x < 192) *(float4*)&v_s[threadIdx.x * 4] = ((const float4*)V)[threadIdx.x];
    __syncthreads();

    const int t = threadIdx.x >> 4;
    const int ls = threadIdx.x & 15;
    const int l = l0 + ls;
    const int X = Xi[b * T_ + t];
    if (!__any(l >= X)) return;

    float a0 = 0.f, a1 = 0.f, a2 = 0.f, a3 = 0.f;
#pragma unroll 4
    for (int h = 0; h < H_; h += 8) {
        float4 w0 = *(const float4*)&we_s[ls][h];
        float4 w1 = *(const float4*)&we_s[ls][h + 4];
        uint4  wd = *(const uint4*)&wd_s[t][h >> 1];
        float4 v0 = *(const float4*)&v_s[h];
        float4 v1 = *(const float4*)&v_s[h + 4];
        a0 = fmaf(selu_core(w0.x + bf_lo(wd.x)), v0.x, a0);
        a1 = fmaf(selu_core(w0.y + bf_hi(wd.x)), v0.y, a1);
        a2 = fmaf(selu_core(w0.z + bf_lo(wd.y)), v0.z, a2);
        a3 = fmaf(selu_core(w0.w + bf_hi(wd.y)), v0.w, a3);
        a0 = fmaf(selu_core(w1.x + bf_lo(wd.z)), v1.x, a0);
        a1 = fmaf(selu_core(w1.y + bf_hi(wd.z)), v1.y, a1);
        a2 = fmaf(selu_core(w1.z + bf_lo(wd.w)), v1.z, a2);
        a3 = fmaf(selu_core(w1.w + bf_hi(wd.w)), v1.w, a3);
    }
    float dot = SELU_SCALE * ((a0 + a1) + (a2 + a3));
    float sc  = dot > 0.0f ? SELU_SCALE * dot
                           : SELU_SCALE * SELU_ALPHA * (__expf(dot) - 1.0f);
    scores[((size_t)(b * T_ + t)) * L_ + l] = sc;
}

// ---------------- per-(b,t) masked logsumexp + gold + mean (atomic) -------------
__global__ __launch_bounds__(64) void loss_k(
        const float* __restrict__ scores, const int* __restrict__ Xi,
        const int* __restrict__ Yi, float* __restrict__ out) {
    const int bt = blockIdx.x;
    const int lane = threadIdx.x;
    const int X = Xi[bt];
    const int Y = Yi[bt];
    const float* row = scores + (size_t)bt * L_;

    float m = -INFINITY;
    for (int l = X + lane; l < L_; l += 64) m = fmaxf(m, row[l]);
#pragma unroll
    for (int off = 32; off > 0; off >>= 1) m = fmaxf(m, __shfl_xor(m, off));

    float s = 0.0f;
    for (int l = X + lane; l < L_; l += 64) s += __expf(row[l] - m);
#pragma unroll
    for (int off = 32; off > 0; off >>= 1) s += __shfl_xor(s, off);

    if (lane == 0)
        atomicAdd(out, (m + __logf(s) - row[Y]) * (1.0f / (B_ * T_)));
}

// ---------------- launch ----------------
extern "C" void kernel_launch(void* const* d_in, const int* in_sizes, int n_in,
                              void* d_out, int out_size, void* d_ws, size_t ws_size,
                              hipStream_t stream) {
    const float* hn  = (const float*)d_in[0];
    const float* dec = (const float*)d_in[1];
    const float* W1  = (const float*)d_in[2];
    const float* W2  = (const float*)d_in[3];
    const float* V   = (const float*)d_in[4];
    const int*   Xi  = (const int*)d_in[5];
    const int*   Yi  = (const int*)d_in[6];
    float* out = (float*)d_out;

    char* ws = (char*)d_ws;
    size_t off = 0;
    auto alloc = [&](size_t bytes) -> char* {
        char* p = ws + off;
        off += (bytes + 255) & ~(size_t)255;
        return p;
    };
    __bf16* web    = (__bf16*)alloc((size_t)B_ * L_ * H_ * 2);
    __bf16* wdb    = (__bf16*)alloc((size_t)B_ * T_ * H_ * 2);
    float*  scores = (float*)alloc((size_t)B_ * T_ * L_ * 4);

    // WE (384 blocks, XCD-swizzled) + WD (12 blocks, self-gathering dj)
    gemm_k<<<396, 256, 0, stream>>>(hn, dec, W1, W2, Yi, web, wdb, out);
    scores_k<<<dim3(B_, L_ / 16), 256, 0, stream>>>(web, wdb, V, Xi, scores);
    loss_k<<<B_ * T_, 64, 0, stream>>>(scores, Xi, Yi, out);
}